// Round 1
// baseline (2165.973 us; speedup 1.0000x reference)
//
#include <hip/hip_runtime.h>

typedef __attribute__((ext_vector_type(4))) float f32x4;
typedef __attribute__((ext_vector_type(8))) __bf16 bf16x8;
typedef __attribute__((ext_vector_type(8))) unsigned short us8;
typedef __attribute__((ext_vector_type(4))) unsigned short us4;

#define AS3(p) ((__attribute__((address_space(3))) void*)(p))
#define AS1(p) ((const __attribute__((address_space(1))) void*)(p))

__device__ __forceinline__ unsigned short f2bf(float f) {
  union { float f; unsigned int u; } v; v.f = f;
  unsigned int r = v.u + 0x7FFFu + ((v.u >> 16) & 1u);
  return (unsigned short)(r >> 16);
}

__device__ __forceinline__ void gld16(const void* g, void* l) {
  __builtin_amdgcn_global_load_lds(AS1(g), AS3(l), 16, 0, 0);
}

#define EXP2F(x) __builtin_amdgcn_exp2f(x)

// ---------------------------------------------------------------------------
// Kernel 0: convert the four weight matrices f32 -> bf16 (ws re-poisoned each call)
// ---------------------------------------------------------------------------
__global__ __launch_bounds__(256) void wconv(const float* __restrict__ Wq, const float* __restrict__ Wk,
                                             const float* __restrict__ Wv, const float* __restrict__ Wo,
                                             unsigned short* __restrict__ Oq, unsigned short* __restrict__ Ok,
                                             unsigned short* __restrict__ Ov, unsigned short* __restrict__ Oo) {
  const float* src; unsigned short* dst;
  switch (blockIdx.y) {
    case 0: src = Wq; dst = Oq; break;
    case 1: src = Wk; dst = Ok; break;
    case 2: src = Wv; dst = Ov; break;
    default: src = Wo; dst = Oo; break;
  }
  int idx = blockIdx.x * 1024 + threadIdx.x * 4;
  float4 f = *(const float4*)(src + idx);
  us4 h;
  h[0] = f2bf(f.x); h[1] = f2bf(f.y); h[2] = f2bf(f.z); h[3] = f2bf(f.w);
  *(us4*)(dst + idx) = h;
}

// ---------------------------------------------------------------------------
// GEMM: C[M=8192, N=1024] = A[M,1024] @ B[N,1024]^T   (B = weight, row-major [n][k])
// 128x128 tile, BK=64, 4 waves (2x2), 16x16x32 bf16 MFMA, XOR-swizzled LDS.
// A_F32: A is f32 (convert during reg-staging); else bf16 via global_load_lds.
// HEADSPLIT: C -> bf16 [B,H,L,Dh]; else C -> f32 row-major [M][1024].
// ---------------------------------------------------------------------------
template<int A_F32, int HEADSPLIT>
__global__ __launch_bounds__(256) void gemm128(const void* __restrict__ Av,
                                               const unsigned short* __restrict__ Bw,
                                               void* __restrict__ Cv) {
  __shared__ unsigned short At[128 * 64];
  __shared__ unsigned short Bt[128 * 64];
  const int tid = threadIdx.x, lane = tid & 63;
  const int w = tid >> 6, wm = w >> 1, wn = w & 1;
  const int tile_n = blockIdx.x * 128, tile_m = blockIdx.y * 128;

  f32x4 acc[4][4];
#pragma unroll
  for (int i = 0; i < 4; ++i)
#pragma unroll
    for (int j = 0; j < 4; ++j) acc[i][j] = (f32x4){0.f, 0.f, 0.f, 0.f};

  for (int kt = 0; kt < 16; ++kt) {
    const int k0 = kt * 64;
    __syncthreads();
    if (A_F32) {
      const float* A = (const float*)Av;
#pragma unroll
      for (int i = 0; i < 4; ++i) {
        int s16 = i * 256 + tid, row = s16 >> 3, sl = s16 & 7, lsl = sl ^ (row & 7);
        const float* ga = A + (size_t)(tile_m + row) * 1024 + k0 + lsl * 8;
        float4 f0 = *(const float4*)ga, f1 = *(const float4*)(ga + 4);
        us8 h;
        h[0] = f2bf(f0.x); h[1] = f2bf(f0.y); h[2] = f2bf(f0.z); h[3] = f2bf(f0.w);
        h[4] = f2bf(f1.x); h[5] = f2bf(f1.y); h[6] = f2bf(f1.z); h[7] = f2bf(f1.w);
        *(us8*)&At[s16 * 8] = h;
      }
    } else {
      const unsigned short* A = (const unsigned short*)Av;
#pragma unroll
      for (int i = 0; i < 4; ++i) {
        int s16 = i * 256 + tid, row = s16 >> 3, sl = s16 & 7, lsl = sl ^ (row & 7);
        gld16(A + (size_t)(tile_m + row) * 1024 + k0 + lsl * 8, &At[s16 * 8]);
      }
    }
#pragma unroll
    for (int i = 0; i < 4; ++i) {
      int s16 = i * 256 + tid, row = s16 >> 3, sl = s16 & 7, lsl = sl ^ (row & 7);
      gld16(Bw + (size_t)(tile_n + row) * 1024 + k0 + lsl * 8, &Bt[s16 * 8]);
    }
    __syncthreads();

#pragma unroll
    for (int ks = 0; ks < 2; ++ks) {
      bf16x8 af[4], bfr[4];
#pragma unroll
      for (int mi = 0; mi < 4; ++mi) {
        int row = wm * 64 + mi * 16 + (lane & 15);
        int p = (ks * 4 + (lane >> 4)) ^ (row & 7);
        af[mi] = *(const bf16x8*)&At[row * 64 + p * 8];
      }
#pragma unroll
      for (int ni = 0; ni < 4; ++ni) {
        int row = wn * 64 + ni * 16 + (lane & 15);
        int p = (ks * 4 + (lane >> 4)) ^ (row & 7);
        bfr[ni] = *(const bf16x8*)&Bt[row * 64 + p * 8];
      }
#pragma unroll
      for (int mi = 0; mi < 4; ++mi)
#pragma unroll
        for (int ni = 0; ni < 4; ++ni)
          acc[mi][ni] = __builtin_amdgcn_mfma_f32_16x16x32_bf16(af[mi], bfr[ni], acc[mi][ni], 0, 0, 0);
    }
  }

#pragma unroll
  for (int mi = 0; mi < 4; ++mi)
#pragma unroll
    for (int ni = 0; ni < 4; ++ni)
#pragma unroll
      for (int r = 0; r < 4; ++r) {
        int row = tile_m + wm * 64 + mi * 16 + (lane >> 4) * 4 + r;
        int col = tile_n + wn * 64 + ni * 16 + (lane & 15);
        float val = acc[mi][ni][r];
        if (HEADSPLIT) {
          unsigned short* C = (unsigned short*)Cv;
          int b = row >> 11, l = row & 2047, h = col >> 6, dh = col & 63;
          C[(size_t)((b * 16 + h) * 2048 + l) * 64 + dh] = f2bf(val);
        } else {
          float* C = (float*)Cv;
          C[(size_t)row * 1024 + col] = val;
        }
      }
}

// ---------------------------------------------------------------------------
// V transpose: Vh [bh][k][dh] -> Vt [bh][dh][k]
// ---------------------------------------------------------------------------
__global__ __launch_bounds__(256) void vtrans(const unsigned short* __restrict__ Vh,
                                              unsigned short* __restrict__ Vt) {
  __shared__ unsigned short t[64][72];
  const int kt = blockIdx.x, bh = blockIdx.y, tid = threadIdx.x;
  {
    int kr = tid >> 2, c0 = (tid & 3) * 16;
    const unsigned short* src = Vh + (size_t)bh * 131072 + (size_t)(kt * 64 + kr) * 64 + c0;
    us8 v0 = *(const us8*)src, v1 = *(const us8*)(src + 8);
#pragma unroll
    for (int j = 0; j < 8; ++j) { t[c0 + j][kr] = v0[j]; t[c0 + 8 + j][kr] = v1[j]; }
  }
  __syncthreads();
  {
    int dh = tid >> 2, k0 = (tid & 3) * 16;
    us8 o0, o1;
#pragma unroll
    for (int j = 0; j < 8; ++j) { o0[j] = t[dh][k0 + j]; o1[j] = t[dh][k0 + 8 + j]; }
    unsigned short* dst = Vt + (size_t)bh * 131072 + (size_t)dh * 2048 + kt * 64 + k0;
    *(us8*)dst = o0; *(us8*)(dst + 8) = o1;
  }
}

// ---------------------------------------------------------------------------
// Attention: per (bh, 64-row q-block). Two-pass online softmax.
// Writes attn probs (f32) and merged out_h (bf16).
// ---------------------------------------------------------------------------
__global__ __launch_bounds__(256) void attn_fwd(const unsigned short* __restrict__ Qh,
                                                const unsigned short* __restrict__ Kh,
                                                const unsigned short* __restrict__ Vt,
                                                float* __restrict__ attnO,
                                                unsigned short* __restrict__ outH) {
  const int qt = 31 - blockIdx.x;        // long blocks launch first
  const int bh = blockIdx.y;
  const int b = bh >> 4, h = bh & 15;
  const unsigned short* Qb = Qh + (size_t)bh * 131072;
  const unsigned short* Kb = Kh + (size_t)bh * 131072;
  const unsigned short* Vb = Vt + (size_t)bh * 131072;
  float* attn_b = attnO + (size_t)bh * 4194304;

  __shared__ unsigned short Qt_l[64 * 64];
  __shared__ unsigned short Kt_l[64 * 64];
  __shared__ unsigned short Vl[64 * 64];
  __shared__ unsigned short Pl[4][16 * 64];

  const int tid = threadIdx.x, lane = tid & 63, w = tid >> 6;
  const int klane = lane & 15;
  const int qbase = qt * 64 + w * 16 + (lane >> 4) * 4;   // + r

  // stage Q tile once
#pragma unroll
  for (int i = 0; i < 2; ++i) {
    int s16 = i * 256 + tid, row = s16 >> 3, sl = s16 & 7, lsl = sl ^ (row & 7);
    gld16(Qb + (size_t)(qt * 64 + row) * 64 + lsl * 8, &Qt_l[s16 * 8]);
  }
  __syncthreads();
  bf16x8 aq[2];
#pragma unroll
  for (int ks = 0; ks < 2; ++ks) {
    int row = w * 16 + (lane & 15);
    int p = (ks * 4 + (lane >> 4)) ^ (row & 7);
    aq[ks] = *(const bf16x8*)&Qt_l[row * 64 + p * 8];
  }

  const float c1 = 0.18033688011112043f;  // log2(e) / sqrt(64)
  float m[4], sm[4];
#pragma unroll
  for (int r = 0; r < 4; ++r) { m[r] = -__builtin_inff(); sm[r] = 0.f; }

  // ---- pass 1: softmax stats ----
  for (int kt = 0; kt <= qt; ++kt) {
    __syncthreads();
#pragma unroll
    for (int i = 0; i < 2; ++i) {
      int s16 = i * 256 + tid, row = s16 >> 3, sl = s16 & 7, lsl = sl ^ (row & 7);
      gld16(Kb + (size_t)(kt * 64 + row) * 64 + lsl * 8, &Kt_l[s16 * 8]);
    }
    __syncthreads();

    f32x4 sc[4];
#pragma unroll
    for (int cf = 0; cf < 4; ++cf) sc[cf] = (f32x4){0.f, 0.f, 0.f, 0.f};
#pragma unroll
    for (int ks = 0; ks < 2; ++ks)
#pragma unroll
      for (int cf = 0; cf < 4; ++cf) {
        int row = cf * 16 + (lane & 15);
        int p = (ks * 4 + (lane >> 4)) ^ (row & 7);
        bf16x8 bk = *(const bf16x8*)&Kt_l[row * 64 + p * 8];
        sc[cf] = __builtin_amdgcn_mfma_f32_16x16x32_bf16(aq[ks], bk, sc[cf], 0, 0, 0);
      }

    float xv[4][4];
    const bool diag = (kt == qt);
#pragma unroll
    for (int cf = 0; cf < 4; ++cf)
#pragma unroll
      for (int r = 0; r < 4; ++r) {
        float x = sc[cf][r] * c1;
        if (diag && (kt * 64 + cf * 16 + klane > qbase + r)) x = -__builtin_inff();
        xv[cf][r] = x;
      }
#pragma unroll
    for (int r = 0; r < 4; ++r) {
      float tm = fmaxf(fmaxf(xv[0][r], xv[1][r]), fmaxf(xv[2][r], xv[3][r]));
      tm = fmaxf(tm, __shfl_xor(tm, 1, 16));
      tm = fmaxf(tm, __shfl_xor(tm, 2, 16));
      tm = fmaxf(tm, __shfl_xor(tm, 4, 16));
      tm = fmaxf(tm, __shfl_xor(tm, 8, 16));
      float mn = fmaxf(m[r], tm);
      float ts = EXP2F(xv[0][r] - mn) + EXP2F(xv[1][r] - mn) + EXP2F(xv[2][r] - mn) + EXP2F(xv[3][r] - mn);
      ts += __shfl_xor(ts, 1, 16);
      ts += __shfl_xor(ts, 2, 16);
      ts += __shfl_xor(ts, 4, 16);
      ts += __shfl_xor(ts, 8, 16);
      sm[r] = sm[r] * EXP2F(m[r] - mn) + ts;
      m[r] = mn;
    }
  }
  float inv[4];
#pragma unroll
  for (int r = 0; r < 4; ++r) inv[r] = 1.f / sm[r];

  // ---- pass 2: write probs + PV ----
  f32x4 oacc[4];
#pragma unroll
  for (int nf = 0; nf < 4; ++nf) oacc[nf] = (f32x4){0.f, 0.f, 0.f, 0.f};

  for (int kt = 0; kt <= qt; ++kt) {
    __syncthreads();
#pragma unroll
    for (int i = 0; i < 2; ++i) {
      int s16 = i * 256 + tid, row = s16 >> 3, sl = s16 & 7, lsl = sl ^ (row & 7);
      gld16(Kb + (size_t)(kt * 64 + row) * 64 + lsl * 8, &Kt_l[s16 * 8]);
      gld16(Vb + (size_t)row * 2048 + kt * 64 + lsl * 8, &Vl[s16 * 8]);
    }
    __syncthreads();

    f32x4 sc[4];
#pragma unroll
    for (int cf = 0; cf < 4; ++cf) sc[cf] = (f32x4){0.f, 0.f, 0.f, 0.f};
#pragma unroll
    for (int ks = 0; ks < 2; ++ks)
#pragma unroll
      for (int cf = 0; cf < 4; ++cf) {
        int row = cf * 16 + (lane & 15);
        int p = (ks * 4 + (lane >> 4)) ^ (row & 7);
        bf16x8 bk = *(const bf16x8*)&Kt_l[row * 64 + p * 8];
        sc[cf] = __builtin_amdgcn_mfma_f32_16x16x32_bf16(aq[ks], bk, sc[cf], 0, 0, 0);
      }

    const bool diag = (kt == qt);
#pragma unroll
    for (int cf = 0; cf < 4; ++cf)
#pragma unroll
      for (int r = 0; r < 4; ++r) {
        float x = sc[cf][r] * c1;
        if (diag && (kt * 64 + cf * 16 + klane > qbase + r)) x = -__builtin_inff();
        float p = EXP2F(x - m[r]) * inv[r];
        attn_b[(size_t)(qbase + r) * 2048 + kt * 64 + cf * 16 + klane] = p;
        int prow = (lane >> 4) * 4 + r;
        int pcol = cf * 16 + klane;
        Pl[w][prow * 64 + (pcol ^ ((prow & 7) << 3))] = f2bf(p);
      }

#pragma unroll
    for (int ks = 0; ks < 2; ++ks) {
      int prow = lane & 15;
      int pp = (ks * 4 + (lane >> 4)) ^ (prow & 7);
      bf16x8 pa = *(const bf16x8*)&Pl[w][prow * 64 + pp * 8];
#pragma unroll
      for (int nf = 0; nf < 4; ++nf) {
        int vr = nf * 16 + (lane & 15);
        int pv = (ks * 4 + (lane >> 4)) ^ (vr & 7);
        bf16x8 bv = *(const bf16x8*)&Vl[vr * 64 + pv * 8];
        oacc[nf] = __builtin_amdgcn_mfma_f32_16x16x32_bf16(pa, bv, oacc[nf], 0, 0, 0);
      }
    }
  }

  // ---- zero-fill strictly-upper tiles (coalesced float4) ----
  {
    int rr = tid >> 2, cc = (tid & 3) * 16;
    float4 z4 = make_float4(0.f, 0.f, 0.f, 0.f);
    for (int kt = qt + 1; kt < 32; ++kt) {
      float* p = attn_b + (size_t)(qt * 64 + rr) * 2048 + kt * 64 + cc;
      *(float4*)(p + 0) = z4; *(float4*)(p + 4) = z4;
      *(float4*)(p + 8) = z4; *(float4*)(p + 12) = z4;
    }
  }

  // ---- write merged out_h (bf16) ----
#pragma unroll
  for (int nf = 0; nf < 4; ++nf)
#pragma unroll
    for (int r = 0; r < 4; ++r) {
      int qrow = qbase + r;
      size_t o = ((size_t)b * 2048 + qrow) * 1024 + h * 64 + nf * 16 + klane;
      outH[o] = f2bf(oacc[nf][r]);
    }
}

// ---------------------------------------------------------------------------
extern "C" void kernel_launch(void* const* d_in, const int* in_sizes, int n_in,
                              void* d_out, int out_size, void* d_ws, size_t ws_size,
                              hipStream_t stream) {
  (void)in_sizes; (void)n_in; (void)out_size; (void)ws_size;
  const float* q  = (const float*)d_in[0];
  const float* k  = (const float*)d_in[1];
  const float* v  = (const float*)d_in[2];
  const float* Wq = (const float*)d_in[5];
  const float* Wk = (const float*)d_in[6];
  const float* Wv = (const float*)d_in[7];
  const float* Wo = (const float*)d_in[8];

  char* ws = (char*)d_ws;
  unsigned short* Wqb = (unsigned short*)(ws + (size_t)0);
  unsigned short* Wkb = (unsigned short*)(ws + ((size_t)2 << 20));
  unsigned short* Wvb = (unsigned short*)(ws + ((size_t)4 << 20));
  unsigned short* Wob = (unsigned short*)(ws + ((size_t)6 << 20));
  unsigned short* QH  = (unsigned short*)(ws + ((size_t)8 << 20));
  unsigned short* KH  = (unsigned short*)(ws + ((size_t)24 << 20));
  unsigned short* VH  = (unsigned short*)(ws + ((size_t)40 << 20));
  unsigned short* VT  = (unsigned short*)(ws + ((size_t)56 << 20));
  unsigned short* OH  = (unsigned short*)(ws + ((size_t)72 << 20));

  float* outp  = (float*)d_out;
  float* attnp = outp + 8388608;   // B*Q*D

  wconv<<<dim3(1024, 4), 256, 0, stream>>>(Wq, Wk, Wv, Wo, Wqb, Wkb, Wvb, Wob);
  gemm128<1, 1><<<dim3(8, 64), 256, 0, stream>>>(q, Wqb, QH);
  gemm128<1, 1><<<dim3(8, 64), 256, 0, stream>>>(k, Wkb, KH);
  gemm128<1, 1><<<dim3(8, 64), 256, 0, stream>>>(v, Wvb, VH);
  vtrans<<<dim3(32, 64), 256, 0, stream>>>(VH, VT);
  attn_fwd<<<dim3(32, 64), 256, 0, stream>>>(QH, KH, VT, attnp, OH);
  gemm128<0, 0><<<dim3(8, 64), 256, 0, stream>>>(OH, Wob, outp);
}